// Round 14
// baseline (372.396 us; speedup 1.0000x reference)
//
#include <hip/hip_runtime.h>
#include <hip/hip_bf16.h>

#define N_NODES      150000
#define N_FRAG_NODES 300000
#define N_FRAGS      30000
#define NEDGE        1200000
#define NCNT         (N_NODES + N_FRAG_NODES)   // combined counter array length
#define D            128
#define DV           32          // float4s per f32 row
#define NX16         (N_NODES * 16)             // u16x8 slots in x16 (=2*NEDGE)
#define SCAN_TILE    1024

typedef __attribute__((ext_vector_type(8))) short short8;
typedef __attribute__((ext_vector_type(8))) unsigned short u16x8;
typedef __attribute__((ext_vector_type(4))) float f32x4;

__device__ __forceinline__ unsigned short f2bf(float f) {
    unsigned u = __float_as_uint(f);
    u = (u + 0x7FFFu + ((u >> 16) & 1u)) >> 16;   // RNE
    return (unsigned short)u;
}
__device__ __forceinline__ float bf2f(unsigned short u) {
    return __uint_as_float((unsigned)u << 16);
}

// ---------------- prep: histograms + batch starts + x->bf16 + W fragment tables ----------------
__global__ void k_prep(const int* __restrict__ mapper, const int* __restrict__ batch,
                       const int* __restrict__ ecol, const float4* __restrict__ x4,
                       const float* __restrict__ W_u, const float* __restrict__ W_gcn,
                       int* __restrict__ mcnt, int* __restrict__ ccnt,
                       int* __restrict__ startb, u16x8* __restrict__ x16,
                       short* __restrict__ wfragU, short* __restrict__ wfragG) {
    int i = blockIdx.x * blockDim.x + threadIdx.x;
    if (i < NEDGE) atomicAdd(&ccnt[ecol[i]], 1);
    if (i < N_FRAG_NODES) atomicAdd(&mcnt[mapper[i]], 1);
    if (i <= N_FRAGS) {
        int lo = 0, hi = N_FRAG_NODES;
        while (lo < hi) { int mid = (lo + hi) >> 1; if (batch[mid] < i) lo = mid + 1; else hi = mid; }
        startb[i] = lo;
    }
    if (i < 4096) {
        const float* W = (i < 2048) ? W_u : W_gcn;
        short* wf = (i < 2048) ? wfragU : wfragG;
        int e = i & 2047;
        int nt = e >> 8;
        int kk = (e >> 6) & 3;
        int lane = e & 63;
        int col = nt * 16 + (lane & 15);
        int kb = kk * 32 + ((lane >> 4) << 3);
        short8 v;
        #pragma unroll
        for (int j = 0; j < 8; ++j) v[j] = (short)f2bf(W[(kb + j) * D + col]);
        ((short8*)wf)[e] = v;
    }
    #pragma unroll
    for (int rep = 0; rep < 2; ++rep) {
        int slot = i + rep * NEDGE;
        if (slot < NX16) {
            float4 v0 = x4[(size_t)slot * 2];
            float4 v1 = x4[(size_t)slot * 2 + 1];
            u16x8 o;
            o[0] = f2bf(v0.x); o[1] = f2bf(v0.y); o[2] = f2bf(v0.z); o[3] = f2bf(v0.w);
            o[4] = f2bf(v1.x); o[5] = f2bf(v1.y); o[6] = f2bf(v1.z); o[7] = f2bf(v1.w);
            x16[slot] = o;
        }
    }
}

// ---------------- combined hierarchical scan over [mcnt | ccnt] (450000) ----------------
__global__ void k_scan_tile(const int* __restrict__ cnt, int* __restrict__ combst,
                            int* __restrict__ tsum) {
    __shared__ int buf[SCAN_TILE];
    int tid = threadIdx.x;
    int i = blockIdx.x * SCAN_TILE + tid;
    int v = (i < NCNT) ? cnt[i] : 0;
    buf[tid] = v;
    __syncthreads();
    for (int off = 1; off < SCAN_TILE; off <<= 1) {
        int t = (tid >= off) ? buf[tid - off] : 0;
        __syncthreads();
        buf[tid] += t;
        __syncthreads();
    }
    if (i < NCNT) combst[i] = buf[tid] - v;
    if (tid == SCAN_TILE - 1) tsum[blockIdx.x] = buf[tid];
}

__global__ void k_scan_tsum(int* __restrict__ tsum, int ntiles,
                            int* __restrict__ mstart, int* __restrict__ cstart) {
    __shared__ int buf[SCAN_TILE];
    int tid = threadIdx.x;
    int v = (tid < ntiles) ? tsum[tid] : 0;
    buf[tid] = v;
    __syncthreads();
    for (int off = 1; off < SCAN_TILE; off <<= 1) {
        int t = (tid >= off) ? buf[tid - off] : 0;
        __syncthreads();
        buf[tid] += t;
        __syncthreads();
    }
    if (tid < ntiles) tsum[tid] = buf[tid] - v;
    if (tid == SCAN_TILE - 1) {
        mstart[N_NODES] = N_FRAG_NODES;                  // total of mapper counts
        cstart[N_FRAG_NODES] = buf[tid] - N_FRAG_NODES;  // = NEDGE
    }
}

// scan_add + sval fold
__global__ void k_scan_add(const int* __restrict__ combst, const int* __restrict__ tsum,
                           int* __restrict__ mstart, int* __restrict__ cstart,
                           const int* __restrict__ mapper, const int* __restrict__ cnt,
                           int2* __restrict__ sval) {
    int i = blockIdx.x * blockDim.x + threadIdx.x;
    if (i >= NCNT) return;
    int v = combst[i] + tsum[i >> 10];
    if (i < N_NODES) {
        mstart[i] = v;
    } else {
        int r = i - N_NODES;
        cstart[r] = v - N_FRAG_NODES;
        int2 s;
        s.x = mapper[r];
        s.y = __float_as_int(rsqrtf((float)(cnt[i] + 1)));   // cnt[i] = indegree(r)
        sval[r] = s;
    }
}

// ---------------- shared MFMA phase: stage[64 rows in LDS, swizzled] @ wl -> dst16 ----------------
// stage slot layout: stage[r*16 + (slot ^ (r&7))], slot = 16B-chunk index within the row
template <bool RELU, bool BIAS>
__device__ __forceinline__ void mfma_phase(const short8* __restrict__ wl,
                                           const short8* __restrict__ stage,
                                           const float* __restrict__ bias,
                                           unsigned short* __restrict__ dst16,
                                           int chunk, int rows, int tid) {
    int wv = tid >> 6, lane = tid & 63;
    int lrow = lane & 15;
    int lk8 = (lane >> 4);
    int r16 = wv * 16 + lrow;
    short8 af[4];
    #pragma unroll
    for (int kk = 0; kk < 4; ++kk)
        af[kk] = stage[r16 * 16 + (((kk << 2) + lk8) ^ (r16 & 7))];
    f32x4 acc[8];
    #pragma unroll
    for (int nt = 0; nt < 8; ++nt) acc[nt] = (f32x4)0.f;
    #pragma unroll
    for (int nt = 0; nt < 8; ++nt) {
        #pragma unroll
        for (int kk = 0; kk < 4; ++kk)
            acc[nt] = __builtin_amdgcn_mfma_f32_16x16x32_bf16(
                          af[kk], wl[(nt * 4 + kk) * 64 + lane], acc[nt], 0, 0, 0);
    }
    int orow0 = chunk + wv * 16 + ((lane >> 4) << 2);
    #pragma unroll
    for (int nt = 0; nt < 8; ++nt) {
        int col = nt * 16 + lrow;
        float bv = BIAS ? bias[col] : 0.f;
        #pragma unroll
        for (int reg = 0; reg < 4; ++reg) {
            int orow = orow0 + reg;
            if (orow < rows) {
                float v = acc[nt][reg] + bv;
                if (RELU) v = fmaxf(v, 0.f);
                dst16[(size_t)orow * D + col] = f2bf(v);
            }
        }
    }
}

// ---------------- fused: fragment mean (LDS) -> U GEMM -> fragu16 ----------------
__global__ void __launch_bounds__(256)
k_frag_mm(const u16x8* __restrict__ x16, const int* __restrict__ mapper,
          const int* __restrict__ startb, const short* __restrict__ wfragU,
          const float* __restrict__ b_u, unsigned short* __restrict__ fragu16) {
    __shared__ short8 wl[2048];          // 32 KB
    __shared__ short8 stage[1024];       // 16 KB (64 rows x 16 slots, swizzled)
    int tid = threadIdx.x;
    for (int e = tid; e < 2048; e += 256) wl[e] = ((const short8*)wfragU)[e];
    int g = tid >> 4, lane = tid & 15;
    int chunk = blockIdx.x * 64;
    #pragma unroll
    for (int nn = 0; nn < 4; ++nn) {
        int r = nn * 16 + g;
        int b = chunk + r;
        u16x8 out = (u16x8)0;
        if (b < N_FRAGS) {
            int s = startb[b], e = startb[b + 1];
            float a0[8], a1[8];
            #pragma unroll
            for (int j = 0; j < 8; ++j) { a0[j] = 0.f; a1[j] = 0.f; }
            int j = s;
            for (; j + 2 <= e; j += 2) {
                int m0 = mapper[j], m1 = mapper[j + 1];
                u16x8 v0 = x16[(size_t)m0 * 16 + lane];
                u16x8 v1 = x16[(size_t)m1 * 16 + lane];
                #pragma unroll
                for (int k = 0; k < 8; ++k) { a0[k] += bf2f(v0[k]); a1[k] += bf2f(v1[k]); }
            }
            if (j < e) {
                u16x8 v0 = x16[(size_t)mapper[j] * 16 + lane];
                #pragma unroll
                for (int k = 0; k < 8; ++k) a0[k] += bf2f(v0[k]);
            }
            float c = (float)(e - s); if (c < 1.f) c = 1.f;
            float inv = 1.f / c;
            #pragma unroll
            for (int k = 0; k < 8; ++k) out[k] = f2bf((a0[k] + a1[k]) * inv);
        }
        short8 o;
        #pragma unroll
        for (int k = 0; k < 8; ++k) o[k] = (short)out[k];
        stage[r * 16 + (lane ^ (r & 7))] = o;
    }
    __syncthreads();
    mfma_phase<true, true>(wl, stage, b_u, fragu16, chunk, N_FRAGS, tid);
}

// ---------------- combined CSR fill: mapper values + packed edge records ----------------
__global__ void k_fill(const int* __restrict__ mapper, const int* __restrict__ batch,
                       const int* __restrict__ erow, const int* __restrict__ ecol,
                       const int* __restrict__ mstart, int* __restrict__ mcnt,
                       int* __restrict__ mvals, const int* __restrict__ cstart,
                       int* __restrict__ ccnt, const int2* __restrict__ sval,
                       int2* __restrict__ erecs) {
    int i = blockIdx.x * blockDim.x + threadIdx.x;
    if (i < N_FRAG_NODES) {
        int k = mapper[i];
        int pos = atomicSub(&mcnt[k], 1) - 1;
        mvals[mstart[k] + pos] = batch[i];
    }
    if (i < NEDGE) {
        int c = ecol[i], r = erow[i];
        int pos = atomicSub(&ccnt[c], 1) - 1;
        erecs[cstart[c] + pos] = sval[r];
    }
}

// ---------------- fused: node pooling (LDS) -> W_gcn GEMM -> pw16 ----------------
__global__ void __launch_bounds__(256)
k_pool_mm(const u16x8* __restrict__ x16, const u16x8* __restrict__ fragu8,
          const int* __restrict__ mstart, const int* __restrict__ mvals,
          const short* __restrict__ wfragG, unsigned short* __restrict__ pw16) {
    __shared__ short8 wl[2048];          // 32 KB
    __shared__ short8 stage[1024];       // 16 KB
    int tid = threadIdx.x;
    for (int e = tid; e < 2048; e += 256) wl[e] = ((const short8*)wfragG)[e];
    int g = tid >> 4, lane = tid & 15;
    int chunk = blockIdx.x * 64;
    #pragma unroll
    for (int nn = 0; nn < 4; ++nn) {
        int r = nn * 16 + g;
        int n = chunk + r;
        u16x8 out = (u16x8)0;
        if (n < N_NODES) {
            int s = mstart[n], e = mstart[n + 1];
            if (e > s) {
                float a0[8], a1[8];
                #pragma unroll
                for (int j = 0; j < 8; ++j) { a0[j] = 0.f; a1[j] = 0.f; }
                int t = s;
                for (; t + 2 <= e; t += 2) {
                    int b0 = mvals[t], b1 = mvals[t + 1];
                    u16x8 u0 = fragu8[(size_t)b0 * 16 + lane];
                    u16x8 u1 = fragu8[(size_t)b1 * 16 + lane];
                    #pragma unroll
                    for (int j = 0; j < 8; ++j) { a0[j] += bf2f(u0[j]); a1[j] += bf2f(u1[j]); }
                }
                if (t < e) {
                    u16x8 u0 = fragu8[(size_t)mvals[t] * 16 + lane];
                    #pragma unroll
                    for (int j = 0; j < 8; ++j) a0[j] += bf2f(u0[j]);
                }
                float inv = 1.f / (float)(e - s);
                u16x8 xv = x16[(size_t)n * 16 + lane];
                #pragma unroll
                for (int j = 0; j < 8; ++j)
                    out[j] = f2bf(fmaf(a0[j] + a1[j], inv, bf2f(xv[j])));
            }
        }
        short8 o;
        #pragma unroll
        for (int k = 0; k < 8; ++k) o[k] = (short)out[k];
        stage[r * 16 + (lane ^ (r & 7))] = o;
    }
    __syncthreads();
    mfma_phase<false, false>(wl, stage, nullptr, pw16, chunk, N_NODES, tid);
}

// ---------------- GCN gather (16-lane group per target node, 4x unroll) -> f32 x_out ----------------
__global__ void k_gcn_gather(const int* __restrict__ cstart, const int2* __restrict__ sval,
                             const int2* __restrict__ erecs, const u16x8* __restrict__ pw8,
                             const float* __restrict__ bgcn, f32x4* __restrict__ xout4) {
    int g = threadIdx.x >> 4, lane = threadIdx.x & 15;
    int c = blockIdx.x * 16 + g;
    if (c >= N_FRAG_NODES) return;
    int s = cstart[c], e = cstart[c + 1];
    int2 sv = sval[c];
    float dc = __int_as_float(sv.y);
    float acc0[8], acc1[8], acc2[8], acc3[8];
    #pragma unroll
    for (int j = 0; j < 8; ++j) { acc0[j] = 0.f; acc1[j] = 0.f; acc2[j] = 0.f; acc3[j] = 0.f; }
    int t = s;
    for (; t + 4 <= e; t += 4) {
        int2 r0 = erecs[t];
        int2 r1 = erecs[t + 1];
        int2 r2 = erecs[t + 2];
        int2 r3 = erecs[t + 3];
        u16x8 u0 = pw8[(size_t)r0.x * 16 + lane];
        u16x8 u1 = pw8[(size_t)r1.x * 16 + lane];
        u16x8 u2 = pw8[(size_t)r2.x * 16 + lane];
        u16x8 u3 = pw8[(size_t)r3.x * 16 + lane];
        float w0 = __int_as_float(r0.y), w1 = __int_as_float(r1.y);
        float w2 = __int_as_float(r2.y), w3 = __int_as_float(r3.y);
        #pragma unroll
        for (int j = 0; j < 8; ++j) {
            acc0[j] = fmaf(bf2f(u0[j]), w0, acc0[j]);
            acc1[j] = fmaf(bf2f(u1[j]), w1, acc1[j]);
            acc2[j] = fmaf(bf2f(u2[j]), w2, acc2[j]);
            acc3[j] = fmaf(bf2f(u3[j]), w3, acc3[j]);
        }
    }
    for (; t < e; ++t) {
        int2 r0 = erecs[t];
        u16x8 u0 = pw8[(size_t)r0.x * 16 + lane];
        float w0 = __int_as_float(r0.y);
        #pragma unroll
        for (int j = 0; j < 8; ++j) acc0[j] = fmaf(bf2f(u0[j]), w0, acc0[j]);
    }
    u16x8 su = pw8[(size_t)sv.x * 16 + lane];
    float dc2 = dc * dc;
    const float4* bg4 = (const float4*)bgcn;
    float4 b0 = bg4[lane * 2], b1 = bg4[lane * 2 + 1];
    float o[8];
    #pragma unroll
    for (int j = 0; j < 8; ++j)
        o[j] = fmaf((acc0[j] + acc1[j]) + (acc2[j] + acc3[j]), dc, bf2f(su[j]) * dc2);
    f32x4 o0 = {o[0] + b0.x, o[1] + b0.y, o[2] + b0.z, o[3] + b0.w};
    f32x4 o1 = {o[4] + b1.x, o[5] + b1.y, o[6] + b1.z, o[7] + b1.w};
    __builtin_nontemporal_store(o0, &xout4[(size_t)c * DV + lane * 2]);
    __builtin_nontemporal_store(o1, &xout4[(size_t)c * DV + lane * 2 + 1]);
}

// ---------------- fragment_x[b] = mean_{j in seg(b)} xout[j]  (4x unroll) ----------------
__global__ void k_frag_x(const float4* __restrict__ x4, const int* __restrict__ startb,
                         float4* __restrict__ fout4) {
    int g = threadIdx.x >> 5, lane = threadIdx.x & 31;
    int b = blockIdx.x * 8 + g;
    if (b >= N_FRAGS) return;
    int s = startb[b], e = startb[b + 1];
    float4 s0 = {0.f,0.f,0.f,0.f}, s1 = {0.f,0.f,0.f,0.f};
    float4 s2 = {0.f,0.f,0.f,0.f}, s3 = {0.f,0.f,0.f,0.f};
    int j = s;
    for (; j + 4 <= e; j += 4) {
        float4 v0 = x4[(size_t)j * DV + lane];
        float4 v1 = x4[(size_t)(j + 1) * DV + lane];
        float4 v2 = x4[(size_t)(j + 2) * DV + lane];
        float4 v3 = x4[(size_t)(j + 3) * DV + lane];
        s0.x += v0.x; s0.y += v0.y; s0.z += v0.z; s0.w += v0.w;
        s1.x += v1.x; s1.y += v1.y; s1.z += v1.z; s1.w += v1.w;
        s2.x += v2.x; s2.y += v2.y; s2.z += v2.z; s2.w += v2.w;
        s3.x += v3.x; s3.y += v3.y; s3.z += v3.z; s3.w += v3.w;
    }
    for (; j < e; ++j) {
        float4 v0 = x4[(size_t)j * DV + lane];
        s0.x += v0.x; s0.y += v0.y; s0.z += v0.z; s0.w += v0.w;
    }
    float4 r = {0.f, 0.f, 0.f, 0.f};
    if (e > s) {
        float inv = 1.f / (float)(e - s);
        r.x = ((s0.x + s1.x) + (s2.x + s3.x)) * inv;
        r.y = ((s0.y + s1.y) + (s2.y + s3.y)) * inv;
        r.z = ((s0.z + s1.z) + (s2.z + s3.z)) * inv;
        r.w = ((s0.w + s1.w) + (s2.w + s3.w)) * inv;
    }
    fout4[(size_t)b * DV + lane] = r;
}

extern "C" void kernel_launch(void* const* d_in, const int* in_sizes, int n_in,
                              void* d_out, int out_size, void* d_ws, size_t ws_size,
                              hipStream_t stream) {
    const float* x      = (const float*)d_in[0];         // f32 [N_NODES, D]
    const int*   mapper = (const int*)d_in[1];
    const int*   batch  = (const int*)d_in[2];
    const int*   erow   = (const int*)d_in[3];           // edge_index[0] (source)
    const int*   ecol   = erow + NEDGE;                  // edge_index[1] (target)
    const float* W_u    = (const float*)d_in[4];
    const float* b_u    = (const float*)d_in[5];
    const float* W_gcn  = (const float*)d_in[6];
    const float* b_gcn  = (const float*)d_in[7];

    float* fout = (float*)d_out;                         // f32 [N_FRAGS, D]
    float* xout = fout + (size_t)N_FRAGS * D;            // f32 [N_FRAG_NODES, D]

    // ---- workspace layout (~105 MB; 16B alignment maintained) ----
    short*  wfragU   = (short*)d_ws;                     // 32 KB
    short*  wfragG   = wfragU + 16384;                   // 32 KB
    int2*   erecs    = (int2*)(wfragG + 16384);          // 1,200,000 int2 (9.6 MB)
    int2*   sval     = erecs + NEDGE;                    // 300,000 int2 (2.4 MB)
    unsigned short* x16      = (unsigned short*)(sval + N_FRAG_NODES); // 150000*128 bf16 (38.4 MB)
    unsigned short* fragu16  = x16 + (size_t)N_NODES * D;              // 30000*128 bf16 (7.7 MB)
    unsigned short* pw16     = fragu16 + (size_t)N_FRAGS * D;          // 150000*128 bf16 (38.4 MB)
    int*    startb = (int*)(pw16 + (size_t)N_NODES * D); // 30,001
    int*    mstart = startb + (N_FRAGS + 1);             // 150,001
    int*    cstart = mstart + (N_NODES + 1);             // 300,001
    int*    mcnt   = cstart + (N_FRAG_NODES + 1);        // 150,000  (memset 0)
    int*    ccnt   = mcnt + N_NODES;                     // 300,000  (memset 0, contiguous after mcnt)
    int*    mvals  = ccnt + N_FRAG_NODES;                // 300,000
    int*    combst = mvals + N_FRAG_NODES;               // 450,000
    int*    tsum   = combst + NCNT;                      // 1,024

    hipMemsetAsync(mcnt, 0, (size_t)NCNT * sizeof(int), stream);

    // histograms + batch segment starts + x16 conversion + W fragment tables
    k_prep<<<(NEDGE + 255) / 256, 256, 0, stream>>>(mapper, batch, ecol, (const float4*)x,
                                                    W_u, W_gcn, mcnt, ccnt, startb,
                                                    (u16x8*)x16, wfragU, wfragG);

    // combined scan of [mcnt | ccnt] -> mstart / cstart (+ sval fold)
    int ntiles = (NCNT + SCAN_TILE - 1) / SCAN_TILE;     // 440
    k_scan_tile<<<ntiles, SCAN_TILE, 0, stream>>>(mcnt, combst, tsum);
    k_scan_tsum<<<1, SCAN_TILE, 0, stream>>>(tsum, ntiles, mstart, cstart);
    k_scan_add<<<(NCNT + 255) / 256, 256, 0, stream>>>(combst, tsum, mstart, cstart,
                                                       mapper, mcnt, sval);

    // fused fragment-mean + U GEMM -> fragu16
    k_frag_mm<<<(N_FRAGS + 63) / 64, 256, 0, stream>>>((const u16x8*)x16, mapper, startb,
                                                       wfragU, b_u, fragu16);

    // combined CSR fill (mapper + edges)
    k_fill<<<(NEDGE + 255) / 256, 256, 0, stream>>>(mapper, batch, erow, ecol,
                                                    mstart, mcnt, mvals,
                                                    cstart, ccnt, sval, erecs);

    // fused node-pooling + W_gcn GEMM -> pw16
    k_pool_mm<<<(N_NODES + 63) / 64, 256, 0, stream>>>((const u16x8*)x16, (const u16x8*)fragu16,
                                                       mstart, mvals, wfragG, pw16);

    // GCN aggregation (gather, bf16 rows) -> f32 x_out
    k_gcn_gather<<<(N_FRAG_NODES + 15) / 16, 256, 0, stream>>>(cstart, sval, erecs,
                                                               (const u16x8*)pw16,
                                                               b_gcn, (f32x4*)xout);
    // fragment mean of x_out
    k_frag_x<<<(N_FRAGS + 7) / 8, 256, 0, stream>>>((const float4*)xout, startb, (float4*)fout);
}

// Round 15
// 354.538 us; speedup vs baseline: 1.0504x; 1.0504x over previous
//
#include <hip/hip_runtime.h>
#include <hip/hip_bf16.h>

#define N_NODES      150000
#define N_FRAG_NODES 300000
#define N_FRAGS      30000
#define NEDGE        1200000
#define NCNT         (N_NODES + N_FRAG_NODES)   // combined counter array length
#define D            128
#define DV           32          // float4s per f32 row
#define NX16         (N_NODES * 16)             // u16x8 slots in x16 (=2*NEDGE)
#define SCAN_TILE    1024

typedef __attribute__((ext_vector_type(8))) short short8;
typedef __attribute__((ext_vector_type(8))) unsigned short u16x8;
typedef __attribute__((ext_vector_type(4))) float f32x4;

__device__ __forceinline__ unsigned short f2bf(float f) {
    unsigned u = __float_as_uint(f);
    u = (u + 0x7FFFu + ((u >> 16) & 1u)) >> 16;   // RNE
    return (unsigned short)u;
}
__device__ __forceinline__ float bf2f(unsigned short u) {
    return __uint_as_float((unsigned)u << 16);
}

// ---------------- prep: histograms + batch starts + x->bf16 + W fragment tables ----------------
__global__ void k_prep(const int* __restrict__ mapper, const int* __restrict__ batch,
                       const int* __restrict__ ecol, const float4* __restrict__ x4,
                       const float* __restrict__ W_u, const float* __restrict__ W_gcn,
                       int* __restrict__ mcnt, int* __restrict__ ccnt,
                       int* __restrict__ startb, u16x8* __restrict__ x16,
                       short* __restrict__ wfragU, short* __restrict__ wfragG) {
    int i = blockIdx.x * blockDim.x + threadIdx.x;
    if (i < NEDGE) atomicAdd(&ccnt[ecol[i]], 1);
    if (i < N_FRAG_NODES) atomicAdd(&mcnt[mapper[i]], 1);
    if (i <= N_FRAGS) {
        int lo = 0, hi = N_FRAG_NODES;
        while (lo < hi) { int mid = (lo + hi) >> 1; if (batch[mid] < i) lo = mid + 1; else hi = mid; }
        startb[i] = lo;
    }
    if (i < 4096) {
        const float* W = (i < 2048) ? W_u : W_gcn;
        short* wf = (i < 2048) ? wfragU : wfragG;
        int e = i & 2047;
        int nt = e >> 8;
        int kk = (e >> 6) & 3;
        int lane = e & 63;
        int col = nt * 16 + (lane & 15);
        int kb = kk * 32 + ((lane >> 4) << 3);
        short8 v;
        #pragma unroll
        for (int j = 0; j < 8; ++j) v[j] = (short)f2bf(W[(kb + j) * D + col]);
        ((short8*)wf)[e] = v;
    }
    #pragma unroll
    for (int rep = 0; rep < 2; ++rep) {
        int slot = i + rep * NEDGE;
        if (slot < NX16) {
            float4 v0 = x4[(size_t)slot * 2];
            float4 v1 = x4[(size_t)slot * 2 + 1];
            u16x8 o;
            o[0] = f2bf(v0.x); o[1] = f2bf(v0.y); o[2] = f2bf(v0.z); o[3] = f2bf(v0.w);
            o[4] = f2bf(v1.x); o[5] = f2bf(v1.y); o[6] = f2bf(v1.z); o[7] = f2bf(v1.w);
            x16[slot] = o;
        }
    }
}

// ---------------- combined hierarchical scan over [mcnt | ccnt] (450000) ----------------
__global__ void k_scan_tile(const int* __restrict__ cnt, int* __restrict__ combst,
                            int* __restrict__ tsum) {
    __shared__ int buf[SCAN_TILE];
    int tid = threadIdx.x;
    int i = blockIdx.x * SCAN_TILE + tid;
    int v = (i < NCNT) ? cnt[i] : 0;
    buf[tid] = v;
    __syncthreads();
    for (int off = 1; off < SCAN_TILE; off <<= 1) {
        int t = (tid >= off) ? buf[tid - off] : 0;
        __syncthreads();
        buf[tid] += t;
        __syncthreads();
    }
    if (i < NCNT) combst[i] = buf[tid] - v;
    if (tid == SCAN_TILE - 1) tsum[blockIdx.x] = buf[tid];
}

__global__ void k_scan_tsum(int* __restrict__ tsum, int ntiles,
                            int* __restrict__ mstart, int* __restrict__ cstart) {
    __shared__ int buf[SCAN_TILE];
    int tid = threadIdx.x;
    int v = (tid < ntiles) ? tsum[tid] : 0;
    buf[tid] = v;
    __syncthreads();
    for (int off = 1; off < SCAN_TILE; off <<= 1) {
        int t = (tid >= off) ? buf[tid - off] : 0;
        __syncthreads();
        buf[tid] += t;
        __syncthreads();
    }
    if (tid < ntiles) tsum[tid] = buf[tid] - v;
    if (tid == SCAN_TILE - 1) {
        mstart[N_NODES] = N_FRAG_NODES;                  // total of mapper counts
        cstart[N_FRAG_NODES] = buf[tid] - N_FRAG_NODES;  // = NEDGE
    }
}

// scan_add + sval fold: cstart write and per-source packed (mapper, rsqrt(indeg+1))
__global__ void k_scan_add(const int* __restrict__ combst, const int* __restrict__ tsum,
                           int* __restrict__ mstart, int* __restrict__ cstart,
                           const int* __restrict__ mapper, const int* __restrict__ cnt,
                           int2* __restrict__ sval) {
    int i = blockIdx.x * blockDim.x + threadIdx.x;
    if (i >= NCNT) return;
    int v = combst[i] + tsum[i >> 10];
    if (i < N_NODES) {
        mstart[i] = v;
    } else {
        int r = i - N_NODES;
        cstart[r] = v - N_FRAG_NODES;
        int2 s;
        s.x = mapper[r];
        s.y = __float_as_int(rsqrtf((float)(cnt[i] + 1)));   // cnt[i] = indegree(r)
        sval[r] = s;
    }
}

// ---------------- frag16[b] = bf16( mean_{j in seg(b)} x16[mapper[j]] )  (16-lane, 4x unroll) ----------------
__global__ void k_frag_mean(const u16x8* __restrict__ x16, const int* __restrict__ mapper,
                            const int* __restrict__ startb, u16x8* __restrict__ frag16) {
    int g = threadIdx.x >> 4, lane = threadIdx.x & 15;
    int b = blockIdx.x * 16 + g;
    if (b >= N_FRAGS) return;
    int s = startb[b], e = startb[b + 1];
    float a0[8], a1[8], a2[8], a3[8];
    #pragma unroll
    for (int j = 0; j < 8; ++j) { a0[j] = 0.f; a1[j] = 0.f; a2[j] = 0.f; a3[j] = 0.f; }
    int j = s;
    for (; j + 4 <= e; j += 4) {
        int m0 = mapper[j], m1 = mapper[j + 1], m2 = mapper[j + 2], m3 = mapper[j + 3];
        u16x8 v0 = x16[(size_t)m0 * 16 + lane];
        u16x8 v1 = x16[(size_t)m1 * 16 + lane];
        u16x8 v2 = x16[(size_t)m2 * 16 + lane];
        u16x8 v3 = x16[(size_t)m3 * 16 + lane];
        #pragma unroll
        for (int k = 0; k < 8; ++k) {
            a0[k] += bf2f(v0[k]); a1[k] += bf2f(v1[k]);
            a2[k] += bf2f(v2[k]); a3[k] += bf2f(v3[k]);
        }
    }
    for (; j < e; ++j) {
        int m0 = mapper[j];
        u16x8 v0 = x16[(size_t)m0 * 16 + lane];
        #pragma unroll
        for (int k = 0; k < 8; ++k) a0[k] += bf2f(v0[k]);
    }
    float c = (float)(e - s); if (c < 1.f) c = 1.f;
    float inv = 1.f / c;
    u16x8 r;
    #pragma unroll
    for (int k = 0; k < 8; ++k)
        r[k] = f2bf(((a0[k] + a1[k]) + (a2[k] + a3[k])) * inv);
    frag16[(size_t)b * 16 + lane] = r;
}

// ---------------- dst16[r] = bf16( act(src16[r] @ W + b) ) via MFMA; in-place safe ----------------
template <bool RELU, bool BIAS>
__global__ void __launch_bounds__(256)
k_rowmat_mfma(const unsigned short* __restrict__ src16, const short* __restrict__ wfrag,
              const float* __restrict__ bias, unsigned short* __restrict__ dst16, int rows) {
    __shared__ short8 wl[2048];          // 32 KB
    int tid = threadIdx.x;
    for (int e = tid; e < 2048; e += 256) wl[e] = ((const short8*)wfrag)[e];
    __syncthreads();
    int wv = tid >> 6, lane = tid & 63;
    int lrow = lane & 15;
    int lk8 = (lane >> 4);               // which short8 within a 32-chunk
    float bv[8];
    #pragma unroll
    for (int nt = 0; nt < 8; ++nt) bv[nt] = BIAS ? bias[nt * 16 + lrow] : 0.f;

    int chunk = blockIdx.x * 64;
    {
        int r = chunk + wv * 16 + lrow;
        short8 af[4];
        if (r < rows) {
            const short8* rowp = (const short8*)(src16 + (size_t)r * D);
            #pragma unroll
            for (int kk = 0; kk < 4; ++kk) af[kk] = rowp[kk * 4 + lk8];
        } else {
            #pragma unroll
            for (int kk = 0; kk < 4; ++kk) af[kk] = (short8)0;
        }
        f32x4 acc[8];
        #pragma unroll
        for (int nt = 0; nt < 8; ++nt) acc[nt] = (f32x4)0.f;
        #pragma unroll
        for (int nt = 0; nt < 8; ++nt) {
            #pragma unroll
            for (int kk = 0; kk < 4; ++kk)
                acc[nt] = __builtin_amdgcn_mfma_f32_16x16x32_bf16(
                              af[kk], wl[(nt * 4 + kk) * 64 + lane], acc[nt], 0, 0, 0);
        }
        int orow0 = chunk + wv * 16 + ((lane >> 4) << 2);
        #pragma unroll
        for (int nt = 0; nt < 8; ++nt) {
            int col = nt * 16 + lrow;
            #pragma unroll
            for (int reg = 0; reg < 4; ++reg) {
                int orow = orow0 + reg;
                if (orow < rows) {
                    float v = acc[nt][reg] + bv[nt];
                    if (RELU) v = fmaxf(v, 0.f);
                    dst16[(size_t)orow * D + col] = f2bf(v);
                }
            }
        }
    }
}

// ---------------- combined CSR fill: mapper values + packed edge records ----------------
__global__ void k_fill(const int* __restrict__ mapper, const int* __restrict__ batch,
                       const int* __restrict__ erow, const int* __restrict__ ecol,
                       const int* __restrict__ mstart, int* __restrict__ mcnt,
                       int* __restrict__ mvals, const int* __restrict__ cstart,
                       int* __restrict__ ccnt, const int2* __restrict__ sval,
                       int2* __restrict__ erecs) {
    int i = blockIdx.x * blockDim.x + threadIdx.x;
    if (i < N_FRAG_NODES) {
        int k = mapper[i];
        int pos = atomicSub(&mcnt[k], 1) - 1;
        mvals[mstart[k] + pos] = batch[i];
    }
    if (i < NEDGE) {
        int c = ecol[i], r = erow[i];
        int pos = atomicSub(&ccnt[c], 1) - 1;
        erecs[cstart[c] + pos] = sval[r];
    }
}

// ---------------- pooled16[n] = bf16( x16[n] + mean_t fragu16[mvals[t]] )  (16-lane, 4x unroll) ----------------
__global__ void k_pool_csr(const u16x8* __restrict__ x16, const u16x8* __restrict__ fragu8,
                           const int* __restrict__ mstart, const int* __restrict__ mvals,
                           u16x8* __restrict__ pooled8) {
    int g = threadIdx.x >> 4, lane = threadIdx.x & 15;
    int n = blockIdx.x * 16 + g;
    if (n >= N_NODES) return;
    int s = mstart[n], e = mstart[n + 1];
    u16x8 out = (u16x8)0;                // bf16 zeros
    if (e > s) {
        float a0[8], a1[8], a2[8], a3[8];
        #pragma unroll
        for (int j = 0; j < 8; ++j) { a0[j] = 0.f; a1[j] = 0.f; a2[j] = 0.f; a3[j] = 0.f; }
        int t = s;
        for (; t + 4 <= e; t += 4) {
            int b0 = mvals[t], b1 = mvals[t + 1], b2 = mvals[t + 2], b3 = mvals[t + 3];
            u16x8 u0 = fragu8[(size_t)b0 * 16 + lane];
            u16x8 u1 = fragu8[(size_t)b1 * 16 + lane];
            u16x8 u2 = fragu8[(size_t)b2 * 16 + lane];
            u16x8 u3 = fragu8[(size_t)b3 * 16 + lane];
            #pragma unroll
            for (int j = 0; j < 8; ++j) {
                a0[j] += bf2f(u0[j]); a1[j] += bf2f(u1[j]);
                a2[j] += bf2f(u2[j]); a3[j] += bf2f(u3[j]);
            }
        }
        for (; t < e; ++t) {
            u16x8 u0 = fragu8[(size_t)mvals[t] * 16 + lane];
            #pragma unroll
            for (int j = 0; j < 8; ++j) a0[j] += bf2f(u0[j]);
        }
        float inv = 1.f / (float)(e - s);
        u16x8 xv = x16[(size_t)n * 16 + lane];
        #pragma unroll
        for (int j = 0; j < 8; ++j)
            out[j] = f2bf(fmaf((a0[j] + a1[j]) + (a2[j] + a3[j]), inv, bf2f(xv[j])));
    }
    pooled8[(size_t)n * 16 + lane] = out;
}

// ---------------- GCN gather (16-lane group per target node, 4x unroll) -> f32 x_out ----------------
__global__ void k_gcn_gather(const int* __restrict__ cstart, const int2* __restrict__ sval,
                             const int2* __restrict__ erecs, const u16x8* __restrict__ pw8,
                             const float* __restrict__ bgcn, f32x4* __restrict__ xout4) {
    int g = threadIdx.x >> 4, lane = threadIdx.x & 15;
    int c = blockIdx.x * 16 + g;
    if (c >= N_FRAG_NODES) return;
    int s = cstart[c], e = cstart[c + 1];
    int2 sv = sval[c];
    float dc = __int_as_float(sv.y);
    float acc0[8], acc1[8], acc2[8], acc3[8];
    #pragma unroll
    for (int j = 0; j < 8; ++j) { acc0[j] = 0.f; acc1[j] = 0.f; acc2[j] = 0.f; acc3[j] = 0.f; }
    int t = s;
    for (; t + 4 <= e; t += 4) {
        int2 r0 = erecs[t];
        int2 r1 = erecs[t + 1];
        int2 r2 = erecs[t + 2];
        int2 r3 = erecs[t + 3];
        u16x8 u0 = pw8[(size_t)r0.x * 16 + lane];
        u16x8 u1 = pw8[(size_t)r1.x * 16 + lane];
        u16x8 u2 = pw8[(size_t)r2.x * 16 + lane];
        u16x8 u3 = pw8[(size_t)r3.x * 16 + lane];
        float w0 = __int_as_float(r0.y), w1 = __int_as_float(r1.y);
        float w2 = __int_as_float(r2.y), w3 = __int_as_float(r3.y);
        #pragma unroll
        for (int j = 0; j < 8; ++j) {
            acc0[j] = fmaf(bf2f(u0[j]), w0, acc0[j]);
            acc1[j] = fmaf(bf2f(u1[j]), w1, acc1[j]);
            acc2[j] = fmaf(bf2f(u2[j]), w2, acc2[j]);
            acc3[j] = fmaf(bf2f(u3[j]), w3, acc3[j]);
        }
    }
    for (; t < e; ++t) {
        int2 r0 = erecs[t];
        u16x8 u0 = pw8[(size_t)r0.x * 16 + lane];
        float w0 = __int_as_float(r0.y);
        #pragma unroll
        for (int j = 0; j < 8; ++j) acc0[j] = fmaf(bf2f(u0[j]), w0, acc0[j]);
    }
    u16x8 su = pw8[(size_t)sv.x * 16 + lane];
    float dc2 = dc * dc;
    const float4* bg4 = (const float4*)bgcn;
    float4 b0 = bg4[lane * 2], b1 = bg4[lane * 2 + 1];
    float o[8];
    #pragma unroll
    for (int j = 0; j < 8; ++j)
        o[j] = fmaf((acc0[j] + acc1[j]) + (acc2[j] + acc3[j]), dc, bf2f(su[j]) * dc2);
    f32x4 o0 = {o[0] + b0.x, o[1] + b0.y, o[2] + b0.z, o[3] + b0.w};
    f32x4 o1 = {o[4] + b1.x, o[5] + b1.y, o[6] + b1.z, o[7] + b1.w};
    __builtin_nontemporal_store(o0, &xout4[(size_t)c * DV + lane * 2]);
    __builtin_nontemporal_store(o1, &xout4[(size_t)c * DV + lane * 2 + 1]);
}

// ---------------- fragment_x[b] = mean_{j in seg(b)} xout[j]  (4x unroll) ----------------
__global__ void k_frag_x(const float4* __restrict__ x4, const int* __restrict__ startb,
                         float4* __restrict__ fout4) {
    int g = threadIdx.x >> 5, lane = threadIdx.x & 31;
    int b = blockIdx.x * 8 + g;
    if (b >= N_FRAGS) return;
    int s = startb[b], e = startb[b + 1];
    float4 s0 = {0.f,0.f,0.f,0.f}, s1 = {0.f,0.f,0.f,0.f};
    float4 s2 = {0.f,0.f,0.f,0.f}, s3 = {0.f,0.f,0.f,0.f};
    int j = s;
    for (; j + 4 <= e; j += 4) {
        float4 v0 = x4[(size_t)j * DV + lane];
        float4 v1 = x4[(size_t)(j + 1) * DV + lane];
        float4 v2 = x4[(size_t)(j + 2) * DV + lane];
        float4 v3 = x4[(size_t)(j + 3) * DV + lane];
        s0.x += v0.x; s0.y += v0.y; s0.z += v0.z; s0.w += v0.w;
        s1.x += v1.x; s1.y += v1.y; s1.z += v1.z; s1.w += v1.w;
        s2.x += v2.x; s2.y += v2.y; s2.z += v2.z; s2.w += v2.w;
        s3.x += v3.x; s3.y += v3.y; s3.z += v3.z; s3.w += v3.w;
    }
    for (; j < e; ++j) {
        float4 v0 = x4[(size_t)j * DV + lane];
        s0.x += v0.x; s0.y += v0.y; s0.z += v0.z; s0.w += v0.w;
    }
    float4 r = {0.f, 0.f, 0.f, 0.f};
    if (e > s) {
        float inv = 1.f / (float)(e - s);
        r.x = ((s0.x + s1.x) + (s2.x + s3.x)) * inv;
        r.y = ((s0.y + s1.y) + (s2.y + s3.y)) * inv;
        r.z = ((s0.z + s1.z) + (s2.z + s3.z)) * inv;
        r.w = ((s0.w + s1.w) + (s2.w + s3.w)) * inv;
    }
    fout4[(size_t)b * DV + lane] = r;
}

extern "C" void kernel_launch(void* const* d_in, const int* in_sizes, int n_in,
                              void* d_out, int out_size, void* d_ws, size_t ws_size,
                              hipStream_t stream) {
    const float* x      = (const float*)d_in[0];         // f32 [N_NODES, D]
    const int*   mapper = (const int*)d_in[1];
    const int*   batch  = (const int*)d_in[2];
    const int*   erow   = (const int*)d_in[3];           // edge_index[0] (source)
    const int*   ecol   = erow + NEDGE;                  // edge_index[1] (target)
    const float* W_u    = (const float*)d_in[4];
    const float* b_u    = (const float*)d_in[5];
    const float* W_gcn  = (const float*)d_in[6];
    const float* b_gcn  = (const float*)d_in[7];

    float* fout = (float*)d_out;                         // f32 [N_FRAGS, D]
    float* xout = fout + (size_t)N_FRAGS * D;            // f32 [N_FRAG_NODES, D]

    // ---- workspace layout (~105 MB; 16B alignment maintained) ----
    short*  wfragU   = (short*)d_ws;                     // 32 KB
    short*  wfragG   = wfragU + 16384;                   // 32 KB
    int2*   erecs    = (int2*)(wfragG + 16384);          // 1,200,000 int2 (9.6 MB)
    int2*   sval     = erecs + NEDGE;                    // 300,000 int2 (2.4 MB)
    unsigned short* x16      = (unsigned short*)(sval + N_FRAG_NODES); // 150000*128 bf16 (38.4 MB)
    unsigned short* frag16   = x16 + (size_t)N_NODES * D;              // 30000*128 bf16 -> fragu16 in place
    unsigned short* pooled16 = frag16 + (size_t)N_FRAGS * D;           // 150000*128 bf16 -> pw16 in place
    int*    startb = (int*)(pooled16 + (size_t)N_NODES * D);           // 30,001
    int*    mstart = startb + (N_FRAGS + 1);             // 150,001
    int*    cstart = mstart + (N_NODES + 1);             // 300,001
    int*    mcnt   = cstart + (N_FRAG_NODES + 1);        // 150,000  (memset 0)
    int*    ccnt   = mcnt + N_NODES;                     // 300,000  (memset 0, contiguous after mcnt)
    int*    mvals  = ccnt + N_FRAG_NODES;                // 300,000
    int*    combst = mvals + N_FRAG_NODES;               // 450,000
    int*    tsum   = combst + NCNT;                      // 1,024

    hipMemsetAsync(mcnt, 0, (size_t)NCNT * sizeof(int), stream);

    // histograms + batch segment starts + x16 conversion + W fragment tables
    k_prep<<<(NEDGE + 255) / 256, 256, 0, stream>>>(mapper, batch, ecol, (const float4*)x,
                                                    W_u, W_gcn, mcnt, ccnt, startb,
                                                    (u16x8*)x16, wfragU, wfragG);

    // combined scan of [mcnt | ccnt] -> mstart / cstart (+ sval fold)
    int ntiles = (NCNT + SCAN_TILE - 1) / SCAN_TILE;     // 440
    k_scan_tile<<<ntiles, SCAN_TILE, 0, stream>>>(mcnt, combst, tsum);
    k_scan_tsum<<<1, SCAN_TILE, 0, stream>>>(tsum, ntiles, mstart, cstart);
    k_scan_add<<<(NCNT + 255) / 256, 256, 0, stream>>>(combst, tsum, mstart, cstart,
                                                       mapper, mcnt, sval);

    // fragment means + U MLP (bf16 pipeline)
    k_frag_mean<<<(N_FRAGS + 15) / 16, 256, 0, stream>>>((const u16x8*)x16, mapper, startb,
                                                         (u16x8*)frag16);
    k_rowmat_mfma<true, true><<<(N_FRAGS + 63) / 64, 256, 0, stream>>>(
        frag16, wfragU, b_u, frag16, N_FRAGS);                           // fragu16 in place

    // combined CSR fill (mapper + edges)
    k_fill<<<(NEDGE + 255) / 256, 256, 0, stream>>>(mapper, batch, erow, ecol,
                                                    mstart, mcnt, mvals,
                                                    cstart, ccnt, sval, erecs);

    // node pooling + W_gcn (bf16 in/out)
    k_pool_csr<<<(N_NODES + 15) / 16, 256, 0, stream>>>((const u16x8*)x16, (const u16x8*)frag16,
                                                        mstart, mvals, (u16x8*)pooled16);
    k_rowmat_mfma<false, false><<<(N_NODES + 63) / 64, 256, 0, stream>>>(
        pooled16, wfragG, nullptr, pooled16, N_NODES);                   // pw16 in place

    // GCN aggregation (gather, bf16 rows) -> f32 x_out
    k_gcn_gather<<<(N_FRAG_NODES + 15) / 16, 256, 0, stream>>>(cstart, sval, erecs,
                                                               (const u16x8*)pooled16,
                                                               b_gcn, (f32x4*)xout);
    // fragment mean of x_out
    k_frag_x<<<(N_FRAGS + 7) / 8, 256, 0, stream>>>((const float4*)xout, startb, (float4*)fout);
}